// Round 18
// baseline (372.062 us; speedup 1.0000x reference)
//
#include <hip/hip_runtime.h>
#include <stdint.h>

typedef short bf16x8 __attribute__((ext_vector_type(8)));
typedef float f32x4  __attribute__((ext_vector_type(4)));

#define GLOAD_LDS16(gp, lp) \
    __builtin_amdgcn_global_load_lds((const __attribute__((address_space(1))) void*)(gp), \
                                     (__attribute__((address_space(3))) void*)(lp), 16, 0, 0)

__device__ __forceinline__ uint32_t bfbits(float f) {
    uint32_t u = __builtin_bit_cast(uint32_t, f);
    u += 0x7FFFu + ((u >> 16) & 1u);   // round-to-nearest-even
    return u >> 16;
}
__device__ __forceinline__ uint32_t pk2(float a, float b) {
    return bfbits(a) | (bfbits(b) << 16);
}

// Fused prep: blocks [0,2048) convert x -> xb (bf16, PADDED [16][194][194][64],
// zero halo, nontemporal x loads); blocks [2048,2624) build
// Wt[t][c][j][ic] = bf16(W[dy][dx][ic][j*4+c]).
__global__ void prep_kernel(const float* __restrict__ x, short* __restrict__ xb,
                            const float* __restrict__ W, short* __restrict__ Wt) {
    const int b = blockIdx.x;
    if (b < 2048) {
        const int total = 16 * 194 * 194 * 8;          // 16B chunks
        for (int i = b * 256 + threadIdx.x; i < total; i += 2048 * 256) {
            int g  = i & 7;
            int t  = i >> 3;
            int wp = t % 194; t /= 194;
            int hp = t % 194;
            int nn = t / 194;
            uint4 r = {0u, 0u, 0u, 0u};
            if (hp >= 1 && hp <= 192 && wp >= 1 && wp <= 192) {
                const float* s = x + (((size_t)nn * 192 + (hp - 1)) * 192 + (wp - 1)) * 64 + g * 8;
                f32x4 a = __builtin_nontemporal_load((const f32x4*)s);
                f32x4 bb = __builtin_nontemporal_load((const f32x4*)(s + 4));
                r.x = pk2(a[0], a[1]); r.y = pk2(a[2], a[3]);
                r.z = pk2(bb[0], bb[1]); r.w = pk2(bb[2], bb[3]);
            }
            *(uint4*)(xb + (size_t)i * 8) = r;
        }
    } else {
        int idx = (b - 2048) * 256 + threadIdx.x;      // 147456
        if (idx < 147456) {
            int t  = idx >> 14;
            int r  = idx & 16383;
            int c  = r >> 12;
            int j  = (r >> 6) & 63;
            int ic = r & 63;
            Wt[idx] = (short)bfbits(W[(t * 64 + ic) * 256 + j * 4 + c]);
        }
    }
}

#define NRING 9
#define ASLOT_B 8448                     // bytes per A h-row slot (66*64*2)
#define SMEM_SHORTS (NRING * ASLOT_B / 2)   // 76,032 B -> 2 blocks/CU

// Implicit-GEMM conv3x3 + bias + pixel_shuffle quadrant, bf16 MFMA.
// B-FRAGMENTS IN REGISTERS: per-(tap,ks) B is tile/wave-invariant -> loaded
// per ks-phase from L2/L1-resident Wt into a 2x16-VGPR dbuf. No B barriers;
// LDS = A-ring only (9 slots), 0.25 ds_read/MFMA. Barriers: 1 mid-tile (ring
// slot h0+8 overwrites h0-1, dead after phase 5) + 1 counted-vmcnt boundary
// per tile = ~12/block vs 108. Double-acc store-spread kept.
__global__ __launch_bounds__(256, 2) void conv_ps_kernel(
    const short* __restrict__ xb, const short* __restrict__ Wt,
    const float* __restrict__ bias, float* __restrict__ out)
{
    __shared__ short smem[SMEM_SHORTS];

    const int tid   = threadIdx.x;
    const int lane  = tid & 63;
    const int wv    = tid >> 6;       // 0..3 : which h-row of the tile
    const int row_l = lane & 15;
    const int grp   = lane >> 4;

    // XCD-aware bijective swizzle (nwg = 1536 % 8 == 0); c innermost.
    const int raw = blockIdx.x;
    const int lb  = (raw & 7) * 192 + (raw >> 3);
    const int c    = lb & 3;
    const int wt   = (lb >> 2) % 3;
    const int hseg = (lb / 12) % 8;
    const int n    = lb / 96;
    const int w0   = wt * 64;
    const int hbase = hseg * 24;
    const int q = c & 1, p = (c >> 1) & 1;

    const short* wsrc = Wt + c * 4096;             // [t][c][j][ic], t-stride 16384

    auto issueA = [&](int row) {                   // 3 gload_lds per wave
        int rowc = row > 192 ? 192 : row;          // clamp (zero-halo rows)
        int slot = (row + 1) % NRING;
        size_t rbase = ((size_t)n * 194 + (rowc + 1)) * 194;
        #pragma unroll
        for (int r = 0; r < 2; ++r) {
            int cch = wv * 132 + r * 64 + lane;    // 0..527
            int wpos = cch >> 3, g = cch & 7, gs = g ^ (wpos & 7);
            GLOAD_LDS16(xb + (rbase + (w0 + wpos)) * 64 + gs * 8,
                        (char*)smem + slot * ASLOT_B + (wv * 132 + r * 64) * 16);
        }
        if (lane < 4) {
            int cch = wv * 132 + 128 + lane;
            int wpos = cch >> 3, g = cch & 7, gs = g ^ (wpos & 7);
            GLOAD_LDS16(xb + (rbase + (w0 + wpos)) * 64 + gs * 8,
                        (char*)smem + slot * ASLOT_B + (wv * 132 + 128) * 16);
        }
    };

    bf16x8 bb0[4], bb1[4];                          // B phase dbuf (16+16 VGPR)

#define LOADB(DST, T, KS) { \
    const short* bp_ = wsrcv + (T) * 16384 + row_l * 64 + ((KS) * 4 + grp) * 8; \
    _Pragma("unroll") for (int nt_ = 0; nt_ < 4; ++nt_) \
        DST[nt_] = *(const bf16x8*)(bp_ + nt_ * 1024); }

    // ---- prologue: A rows hbase-1 .. hbase+4 (6 rows); B phase (0,0) ----
    {
        const short* wsrcv = wsrc;
        #pragma unroll
        for (int r = 0; r < 6; ++r) issueA(hbase - 1 + r);
        LOADB(bb0, 0, 0);
    }
    asm volatile("s_waitcnt vmcnt(0)" ::: "memory");
    __builtin_amdgcn_sched_barrier(0);
    __syncthreads();

    f32x4 bv4[4];
    #pragma unroll
    for (int nt = 0; nt < 4; ++nt) {
        const int j0 = nt * 16 + grp * 4;
        #pragma unroll
        for (int jv = 0; jv < 4; ++jv)
            bv4[nt][jv] = bias[(j0 + jv) * 4 + c];
    }

    f32x4 accA[4][4], accB[4][4];

#define SCHB __builtin_amdgcn_sched_barrier(0)
#define MIDBAR  SCHB; __builtin_amdgcn_s_barrier(); SCHB;
#define BOUND   SCHB; asm volatile("s_waitcnt vmcnt(16)" ::: "memory"); SCHB; \
                __builtin_amdgcn_s_barrier(); SCHB;

// one ks-phase: extras; old-acc stores; issue next-phase B; read 4 A-frags;
// 16 MFMA with current B. Compiler inserts precise lgkm/vm waits.
#define PHX(ACC, DY, DX, KS, BCUR, DOLD, BNXT, NT_, NK_, EXTRA, STS) { \
    EXTRA; \
    STS; \
    if (DOLD) LOADB(BNXT, NT_, NK_); \
    const int rd_ = row_l + (DX); \
    const int a7_ = rd_ & 7; \
    const short* ap_ = &smem[sl[DY] * 4224 + rd_ * 64 + ((((KS) * 4 + grp) ^ a7_) << 3)]; \
    bf16x8 af_[4]; \
    _Pragma("unroll") for (int mt_ = 0; mt_ < 4; ++mt_) \
        af_[mt_] = *(const bf16x8*)(ap_ + mt_ * 1024); \
    _Pragma("unroll") for (int mt_ = 0; mt_ < 4; ++mt_) \
        _Pragma("unroll") for (int nt_ = 0; nt_ < 4; ++nt_) \
            ACC[mt_][nt_] = __builtin_amdgcn_mfma_f32_16x16x32_bf16( \
                BCUR[nt_], af_[mt_], ACC[mt_][nt_], 0, 0, 0); }

#define ST2(ACCO, S) { \
    const int mt_ = (S) >> 1, n0_ = ((S) & 1) * 2; \
    float* po_ = out + ((rowb_o + 2 * (w0 + mt_ * 16 + row_l) + p) * 64 + grp * 4); \
    __builtin_nontemporal_store(ACCO[mt_][n0_],     (f32x4*)(po_ + n0_ * 16)); \
    __builtin_nontemporal_store(ACCO[mt_][n0_ + 1], (f32x4*)(po_ + (n0_ + 1) * 16)); }

#define TILE_HEAD(ACC, ITV) \
    const int h0 = hbase + (ITV) * 4; \
    uint64_t wadr_ = (uint64_t)wsrc; \
    asm volatile("" : "+s"(wadr_)); \
    const short* wsrcv = (const short*)wadr_;   /* opaque: blocks B-load LICM/CSE */ \
    int sl[3]; \
    _Pragma("unroll") for (int dy = 0; dy < 3; ++dy) sl[dy] = (h0 + wv + dy) % NRING; \
    _Pragma("unroll") for (int i = 0; i < 4; ++i) \
        _Pragma("unroll") for (int j = 0; j < 4; ++j) ACC[i][j] = bv4[j];

// generic tile: DOST = store old acc (spread), DORF = issue ring refills,
// DOBD = boundary sync + preload next tile's B(0,0).
#define GTILE(ACC, ACCO, ITV, DOST, DORF, DOBD) { \
    TILE_HEAD(ACC, ITV); \
    const long rowb_o = ((long)(n * 384 + 2 * (h0 - 4 + wv) + q)) * 384; \
    PHX(ACC,0,0,0, bb0,1,bb1,0,1, if (DORF) issueA(h0 + 5), {}); \
    PHX(ACC,0,0,1, bb1,1,bb0,1,0, if (DORF) issueA(h0 + 6), if (DOST) ST2(ACCO,0)); \
    PHX(ACC,0,1,0, bb0,1,bb1,1,1, if (DORF) issueA(h0 + 7), {}); \
    PHX(ACC,0,1,1, bb1,1,bb0,2,0, {}, if (DOST) ST2(ACCO,1)); \
    PHX(ACC,0,2,0, bb0,1,bb1,2,1, {}, {}); \
    PHX(ACC,0,2,1, bb1,1,bb0,3,0, {}, if (DOST) ST2(ACCO,2)); \
    MIDBAR;   /* row h0-1 (slot of refill h0+8) dead: only wave0 dy0 reads it */ \
    PHX(ACC,1,0,0, bb0,1,bb1,3,1, if (DORF) issueA(h0 + 8), {}); \
    PHX(ACC,1,0,1, bb1,1,bb0,4,0, {}, if (DOST) ST2(ACCO,3)); \
    PHX(ACC,1,1,0, bb0,1,bb1,4,1, {}, {}); \
    PHX(ACC,1,1,1, bb1,1,bb0,5,0, {}, if (DOST) ST2(ACCO,4)); \
    PHX(ACC,1,2,0, bb0,1,bb1,5,1, {}, {}); \
    PHX(ACC,1,2,1, bb1,1,bb0,6,0, {}, if (DOST) ST2(ACCO,5)); \
    PHX(ACC,2,0,0, bb0,1,bb1,6,1, {}, {}); \
    PHX(ACC,2,0,1, bb1,1,bb0,7,0, {}, if (DOST) ST2(ACCO,6)); \
    PHX(ACC,2,1,0, bb0,1,bb1,7,1, {}, {}); \
    PHX(ACC,2,1,1, bb1,1,bb0,8,0, {}, if (DOST) ST2(ACCO,7)); \
    PHX(ACC,2,2,0, bb0,1,bb1,8,1, {}, {}); \
    PHX(ACC,2,2,1, bb1,DOBD,bb0,0,0, {}, {}); \
    if (DOBD) { BOUND; } }

    GTILE(accA, accB, 0, 0, 1, 1);
    #pragma unroll 1
    for (int it2 = 1; it2 < 5; it2 += 2) {
        GTILE(accB, accA, it2,     1, 1, 1);
        GTILE(accA, accB, it2 + 1, 1, 1, 1);
    }
    GTILE(accB, accA, 5, 1, 0, 0);

    // final: store tile 5's acc directly
    {
        const int h = hbase + 20 + wv;
        const long rowb = ((long)(n * 384 + 2 * h + q)) * 384;
        #pragma unroll
        for (int mt = 0; mt < 4; ++mt) {
            float* po = out + ((rowb + 2 * (w0 + mt * 16 + row_l) + p) * 64 + grp * 4);
            #pragma unroll
            for (int nt = 0; nt < 4; ++nt)
                __builtin_nontemporal_store(accB[mt][nt], (f32x4*)(po + nt * 16));
        }
    }
#undef GTILE
#undef TILE_HEAD
#undef ST2
#undef PHX
#undef BOUND
#undef MIDBAR
#undef SCHB
#undef LOADB
}

extern "C" void kernel_launch(void* const* d_in, const int* in_sizes, int n_in,
                              void* d_out, int out_size, void* d_ws, size_t ws_size,
                              hipStream_t stream) {
    const float* x = (const float*)d_in[0];
    const float* W = (const float*)d_in[1];
    const float* b = (const float*)d_in[2];
    float* out = (float*)d_out;

    const size_t xb_bytes = (size_t)16 * 194 * 194 * 64 * 2;   // 77,070,336 (padded)
    short* xbuf = (short*)d_ws;
    short* Wt   = (short*)((char*)d_ws + xb_bytes);

    hipLaunchKernelGGL(prep_kernel, dim3(2624), dim3(256), 0, stream, x, xbuf, W, Wt);
    hipLaunchKernelGGL(conv_ps_kernel, dim3(1536), dim3(256), 0, stream, xbuf, Wt, b, out);
}